// Round 15
// baseline (413.061 us; speedup 1.0000x reference)
//
#include <hip/hip_runtime.h>

#define FD 64          // feature dim
#define BRS 256        // rows per bucket
#define BR_SHIFT 8
#define COL_BITS 18
#define COL_MASK 0x3FFFF
#define NBMAX 640      // max bucket count per graph (aff: ceil(150016/256)=587)
#define CH 8192        // edges per chunk
#define CH_SHIFT 13

// ---------------- utility ----------------

static __global__ void zero_int_kernel(int* __restrict__ p, int n) {
    int i = blockIdx.x * blockDim.x + threadIdx.x;
    if (i < n) p[i] = 0;
}

static inline unsigned gridFor(long long n, int block) {
    return (unsigned)((n + block - 1) / block);
}

static __device__ inline unsigned short f2bf(float x) {
    unsigned u = __float_as_uint(x);
    unsigned r = ((u >> 16) & 1u) + 0x7FFFu;
    return (unsigned short)((u + r) >> 16);
}
static __device__ inline float bf2f(unsigned short h) {
    return __uint_as_float((unsigned)h << 16);
}

// ---- non-temporal load/store helpers (streaming data: keep out of L2/L3) ----
typedef float __attribute__((ext_vector_type(4))) f32x4v;
typedef unsigned short __attribute__((ext_vector_type(4))) u16x4v;

static __device__ inline float4 nt_load4(const float4* p) {
    f32x4v v = __builtin_nontemporal_load((const f32x4v*)p);
    return make_float4(v.x, v.y, v.z, v.w);
}
static __device__ inline void nt_store4(float4* p, float4 v) {
    f32x4v t = { v.x, v.y, v.z, v.w };
    __builtin_nontemporal_store(t, (f32x4v*)p);
}
static __device__ inline void nt_storeu4(ushort4* p, ushort4 v) {
    u16x4v t = { v.x, v.y, v.z, v.w };
    __builtin_nontemporal_store(t, (u16x4v*)p);
}
static __device__ inline int nt_loadi(const int* p) {
    return __builtin_nontemporal_load(p);
}

// pack concat(a,b) f32 quads -> bf16 quads, folding column weight f(deg)=1/(sqrt(deg)+eps)
static __global__ void pack2w_bf16_kernel(const float4* __restrict__ a, long long aq,
                                          const float4* __restrict__ b, long long bq,
                                          const int* __restrict__ rp,
                                          ushort4* __restrict__ dst) {
    long long i = (long long)blockIdx.x * blockDim.x + threadIdx.x;
    if (i >= aq + bq) return;
    int node = (int)(i >> 4);
    float w = 1.0f / (sqrtf((float)(rp[node + 1] - rp[node])) + 1e-8f);
    float4 f = (i < aq) ? nt_load4(&a[i]) : nt_load4(&b[i - aq]);
    dst[i] = make_ushort4(f2bf(w * f.x), f2bf(w * f.y), f2bf(w * f.z), f2bf(w * f.w));
}

// plain pack (agg table: weight is row-side only)
static __global__ void pack1_bf16_kernel(const float4* __restrict__ a, long long aq,
                                         ushort4* __restrict__ dst) {
    long long i = (long long)blockIdx.x * blockDim.x + threadIdx.x;
    if (i >= aq) return;
    float4 f = nt_load4(&a[i]);
    dst[i] = make_ushort4(f2bf(f.x), f2bf(f.y), f2bf(f.z), f2bf(f.w));
}

// ---------------- batched CSR build over 3 graphs ----------------
// g0=aff, g1=agg, g2=hist. Edge positions are GLOBAL (offset by graph edge base).

// per-chunk LDS histogram -> per-edge rank (ushort), per-chunk hist h_blk, global gcount
static __global__ void bcount_rank_kernel(const int* __restrict__ r0, const int* __restrict__ r1,
                                          const int* __restrict__ r2,
                                          int nnz0, int nnz1, int nnz2,
                                          int nb0, int nb1, int nb2,
                                          int nch0, int nch1,
                                          int hoff1, int hoff2,
                                          int* __restrict__ gcount,
                                          unsigned short* __restrict__ rank,
                                          int* __restrict__ h_blk) {
    int blk = blockIdx.x;
    const int* rows; int nnz, nb, chl, hbase, gbase; long long ebase;
    if (blk < nch0)              { rows = r0; nnz = nnz0; nb = nb0; chl = blk;               hbase = 0;     gbase = 0;         ebase = 0; }
    else if (blk < nch0 + nch1)  { rows = r1; nnz = nnz1; nb = nb1; chl = blk - nch0;        hbase = hoff1; gbase = nb0;       ebase = nnz0; }
    else                         { rows = r2; nnz = nnz2; nb = nb2; chl = blk - nch0 - nch1; hbase = hoff2; gbase = nb0 + nb1; ebase = (long long)nnz0 + nnz1; }
    __shared__ int h[NBMAX];
    long long c0 = (long long)chl << CH_SHIFT;
    int cnt = (int)(((long long)nnz - c0) < CH ? ((long long)nnz - c0) : CH);
    for (int i = threadIdx.x; i < nb; i += blockDim.x) h[i] = 0;
    __syncthreads();
    for (int i = threadIdx.x; i < cnt; i += blockDim.x)
        rank[ebase + c0 + i] = (unsigned short)atomicAdd(&h[rows[c0 + i] >> BR_SHIFT], 1);
    __syncthreads();
    int* hb = h_blk + hbase + (long long)chl * nb;
    for (int i = threadIdx.x; i < nb; i += blockDim.x) {
        int c = h[i];
        hb[i] = c;
        if (c) atomicAdd(&gcount[gbase + i], c);
    }
}

// one block per graph: exclusive scan of nb_g counts -> bptr (GLOBAL edge positions)
static __global__ void bscan_kernel(const int* __restrict__ gcount,
                                    int nb0, int nb1, int nb2,
                                    int nnz0, int nnz1, int nnz2,
                                    int* __restrict__ bptr) {
    __shared__ int tsum[1024];
    int g = blockIdx.x;
    int nb, gbase, pbase, nnz; long long ebase;
    if (g == 0)      { nb = nb0; gbase = 0;         pbase = 0;             ebase = 0;                       nnz = nnz0; }
    else if (g == 1) { nb = nb1; gbase = nb0;       pbase = nb0 + 1;       ebase = nnz0;                    nnz = nnz1; }
    else             { nb = nb2; gbase = nb0 + nb1; pbase = nb0 + nb1 + 2; ebase = (long long)nnz0 + nnz1;  nnz = nnz2; }
    int k = (nb + 1023) / 1024;
    int start = threadIdx.x * k;
    int s = 0;
    for (int i = 0; i < k; ++i) {
        int idx = start + i;
        if (idx < nb) s += gcount[gbase + idx];
    }
    tsum[threadIdx.x] = s;
    __syncthreads();
    for (int off = 1; off < 1024; off <<= 1) {
        int t = (threadIdx.x >= (unsigned)off) ? tsum[threadIdx.x - off] : 0;
        __syncthreads();
        tsum[threadIdx.x] += t;
        __syncthreads();
    }
    int run = (int)ebase + tsum[threadIdx.x] - s;
    for (int i = 0; i < k; ++i) {
        int idx = start + i;
        if (idx < nb) {
            bptr[pbase + idx] = run;
            run += gcount[gbase + idx];
        }
    }
    if (threadIdx.x == 0) bptr[pbase + nb] = (int)(ebase + nnz);
}

// one wave per bucket: scan per-(chunk,bucket) counts into base offsets (in place)
static __global__ void bchunk_base_kernel(const int* __restrict__ bptr,
                                          int nb0, int nb1, int nb2,
                                          int nch0, int nch1, int nch2,
                                          int hoff1, int hoff2,
                                          int* __restrict__ h_blk) {
    int b = blockIdx.x;
    int bl, nb, nch, hbase, pbase;
    if (b < nb0)            { bl = b;             nb = nb0; nch = nch0; hbase = 0;     pbase = 0; }
    else if (b < nb0 + nb1) { bl = b - nb0;       nb = nb1; nch = nch1; hbase = hoff1; pbase = nb0 + 1; }
    else                    { bl = b - nb0 - nb1; nb = nb2; nch = nch2; hbase = hoff2; pbase = nb0 + nb1 + 2; }
    int lane = threadIdx.x;
    int k = (nch + 63) / 64;
    int i0 = lane * k;
    int s = 0;
    for (int i = 0; i < k; ++i) {
        int blk = i0 + i;
        if (blk < nch) s += h_blk[hbase + (long long)blk * nb + bl];
    }
    int sc = s;
    #pragma unroll
    for (int off = 1; off < 64; off <<= 1) {
        int t = __shfl_up(sc, off);
        if (lane >= off) sc += t;
    }
    int run = bptr[pbase + bl] + sc - s;
    for (int i = 0; i < k; ++i) {
        int blk = i0 + i;
        if (blk < nch) {
            long long o = hbase + (long long)blk * nb + bl;
            int c = h_blk[o];
            h_blk[o] = run;
            run += c;
        }
    }
}

// pure scatter over all graphs: 1 edge/thread; 4B payload
// etmp[pos] = (row % BRS) << COL_BITS | col
static __global__ void bscatter_kernel(const int* __restrict__ r0, const int* __restrict__ c0p,
                                       const int* __restrict__ r1, const int* __restrict__ c1p,
                                       const int* __restrict__ r2, const int* __restrict__ c2p,
                                       int nnz0, int nnz1, int nnz2,
                                       int nb0, int nb1, int nb2,
                                       int hoff1, int hoff2,
                                       const unsigned short* __restrict__ rank,
                                       const int* __restrict__ base_blk,
                                       int* __restrict__ etmp) {
    long long t = (long long)blockIdx.x * blockDim.x + threadIdx.x;
    long long e1 = nnz0, e2 = (long long)nnz0 + nnz1, e3 = e2 + nnz2;
    if (t >= e3) return;
    const int* rows; const int* cols; long long i; int nb, hbase;
    if (t < e1)      { rows = r0; cols = c0p; i = t;      nb = nb0; hbase = 0; }
    else if (t < e2) { rows = r1; cols = c1p; i = t - e1; nb = nb1; hbase = hoff1; }
    else             { rows = r2; cols = c2p; i = t - e2; nb = nb2; hbase = hoff2; }
    int r = rows[i];
    int b = r >> BR_SHIFT;
    int pos = base_blk[hbase + (i >> CH_SHIFT) * (long long)nb + b] + rank[t];
    etmp[pos] = ((r & (BRS - 1)) << COL_BITS) | cols[i];
}

// per-bucket counting sort (256 rows/bucket, 512 threads) -> row-sorted epack + row_ptr
static __global__ void blocal_sort_kernel(const int* __restrict__ bptr,
                                          const int* __restrict__ etmp,
                                          int* __restrict__ epack,
                                          int* __restrict__ row_ptr,
                                          int nb0, int nb1, int nb2,
                                          int n0, int n1g, int n2g,
                                          int roff1, int roff2) {
    __shared__ int cnt[BRS];
    __shared__ int startS[BRS];
    __shared__ int wsum[8];
    int b = blockIdx.x;
    int bl, pbase, rbase, ng, nbg;
    if (b < nb0)            { bl = b;             pbase = 0;             rbase = 0;     ng = n0;  nbg = nb0; }
    else if (b < nb0 + nb1) { bl = b - nb0;       pbase = nb0 + 1;       rbase = roff1; ng = n1g; nbg = nb1; }
    else                    { bl = b - nb0 - nb1; pbase = nb0 + nb1 + 2; rbase = roff2; ng = n2g; nbg = nb2; }
    int beg = bptr[pbase + bl], end = bptr[pbase + bl + 1];
    int tid = threadIdx.x;                 // blockDim = 512
    if (tid < BRS) cnt[tid] = 0;
    __syncthreads();
    for (int e = beg + tid; e < end; e += blockDim.x)
        atomicAdd(&cnt[((unsigned)etmp[e]) >> COL_BITS], 1);
    __syncthreads();
    int v = (tid < BRS) ? cnt[tid] : 0;
    int s = v;
    int lane = tid & 63, wv = tid >> 6;    // waves 0..3 hold the 256 counters
    #pragma unroll
    for (int off = 1; off < 64; off <<= 1) {
        int t = __shfl_up(s, off);
        if (lane >= off) s += t;
    }
    if (tid < BRS && lane == 63) wsum[wv] = s;
    __syncthreads();
    if (tid == 0) {
        int run = 0;
        #pragma unroll
        for (int w = 0; w < BRS / 64; ++w) { int t = wsum[w]; wsum[w] = run; run += t; }
    }
    __syncthreads();
    if (tid < BRS) {
        int ex = s - v + wsum[wv];         // exclusive prefix
        startS[tid] = ex;
        int r = bl * BRS + tid;
        if (r < ng) row_ptr[rbase + r] = beg + ex;
        cnt[tid] = 0;
    }
    __syncthreads();
    for (int e = beg + tid; e < end; e += blockDim.x) {
        int p = etmp[e];
        int rl = ((unsigned)p) >> COL_BITS;
        int rk = atomicAdd(&cnt[rl], 1);
        epack[beg + startS[rl] + rk] = p & COL_MASK;
    }
    if (bl == 0 && tid == 0) row_ptr[rbase + ng] = bptr[pbase + nbg];
}

// ---------------- fused gather SpMM over bf16 table, 16 lanes/row x 4 dims ----------------
// WMODE 0: row weight w = 1/(sqrt(deg)+1e-8)  (sym-normalized graphs)
// WMODE 1: row weight w = 1/(deg+1e-8)        (agg graph)
// s = scale * w_r * sum_e tab16[col_e]   (column weight pre-folded into table)
// Streaming data (epack, acc, base, nxt16, outputs) uses non-temporal hints so
// the gather table keeps L2/L3 residency.
template <int WMODE, bool VIRT_BASE, bool WRITE_NXT16, bool NORM, bool WRITE_ACC>
static __global__ void spmm_gather_bf16_kernel(const int* __restrict__ row_ptr,
                                               const int* __restrict__ epack,
                                               const ushort4* __restrict__ tab16,
                                               const float4* __restrict__ fa4,
                                               const float4* __restrict__ fb4, int split,
                                               ushort4* __restrict__ nxt16,
                                               float4* __restrict__ accbuf4,
                                               float4* __restrict__ out_lo4,
                                               float4* __restrict__ out_hi4,
                                               int out_split, int n, float scale) {
    long long t = (long long)blockIdx.x * blockDim.x + threadIdx.x;
    int r = (int)(t >> 4);
    if (r >= n) return;
    int l = (int)(t & 15);
    int beg = row_ptr[r];
    int end = row_ptr[r + 1];
    float ax = 0.f, ay = 0.f, az = 0.f, aw = 0.f;
    int e = beg;
    for (; e + 7 < end; e += 8) {
        int c0 = nt_loadi(&epack[e]);
        int c1 = nt_loadi(&epack[e + 1]);
        int c2 = nt_loadi(&epack[e + 2]);
        int c3 = nt_loadi(&epack[e + 3]);
        int c4 = nt_loadi(&epack[e + 4]);
        int c5 = nt_loadi(&epack[e + 5]);
        int c6 = nt_loadi(&epack[e + 6]);
        int c7 = nt_loadi(&epack[e + 7]);
        ushort4 h0 = tab16[((long long)c0 << 4) + l];
        ushort4 h1 = tab16[((long long)c1 << 4) + l];
        ushort4 h2 = tab16[((long long)c2 << 4) + l];
        ushort4 h3 = tab16[((long long)c3 << 4) + l];
        ushort4 h4 = tab16[((long long)c4 << 4) + l];
        ushort4 h5 = tab16[((long long)c5 << 4) + l];
        ushort4 h6 = tab16[((long long)c6 << 4) + l];
        ushort4 h7 = tab16[((long long)c7 << 4) + l];
        ax += bf2f(h0.x); ay += bf2f(h0.y); az += bf2f(h0.z); aw += bf2f(h0.w);
        ax += bf2f(h1.x); ay += bf2f(h1.y); az += bf2f(h1.z); aw += bf2f(h1.w);
        ax += bf2f(h2.x); ay += bf2f(h2.y); az += bf2f(h2.z); aw += bf2f(h2.w);
        ax += bf2f(h3.x); ay += bf2f(h3.y); az += bf2f(h3.z); aw += bf2f(h3.w);
        ax += bf2f(h4.x); ay += bf2f(h4.y); az += bf2f(h4.z); aw += bf2f(h4.w);
        ax += bf2f(h5.x); ay += bf2f(h5.y); az += bf2f(h5.z); aw += bf2f(h5.w);
        ax += bf2f(h6.x); ay += bf2f(h6.y); az += bf2f(h6.z); aw += bf2f(h6.w);
        ax += bf2f(h7.x); ay += bf2f(h7.y); az += bf2f(h7.z); aw += bf2f(h7.w);
    }
    for (; e + 3 < end; e += 4) {
        int c0 = nt_loadi(&epack[e]);
        int c1 = nt_loadi(&epack[e + 1]);
        int c2 = nt_loadi(&epack[e + 2]);
        int c3 = nt_loadi(&epack[e + 3]);
        ushort4 h0 = tab16[((long long)c0 << 4) + l];
        ushort4 h1 = tab16[((long long)c1 << 4) + l];
        ushort4 h2 = tab16[((long long)c2 << 4) + l];
        ushort4 h3 = tab16[((long long)c3 << 4) + l];
        ax += bf2f(h0.x); ay += bf2f(h0.y); az += bf2f(h0.z); aw += bf2f(h0.w);
        ax += bf2f(h1.x); ay += bf2f(h1.y); az += bf2f(h1.z); aw += bf2f(h1.w);
        ax += bf2f(h2.x); ay += bf2f(h2.y); az += bf2f(h2.z); aw += bf2f(h2.w);
        ax += bf2f(h3.x); ay += bf2f(h3.y); az += bf2f(h3.z); aw += bf2f(h3.w);
    }
    for (; e < end; ++e) {
        int c = nt_loadi(&epack[e]);
        ushort4 h = tab16[((long long)c << 4) + l];
        ax += bf2f(h.x); ay += bf2f(h.y); az += bf2f(h.z); aw += bf2f(h.w);
    }
    float deg = (float)(end - beg);
    float w = (WMODE == 0) ? (1.0f / (sqrtf(deg) + 1e-8f)) : (1.0f / (deg + 1e-8f));
    float m = scale * w;
    float4 s;
    s.x = ax * m; s.y = ay * m; s.z = az * m; s.w = aw * m;
    long long idx = ((long long)r << 4) + l;
    if (WRITE_NXT16)  // layer-2 table entry: f_r * s_r
        nt_storeu4(&nxt16[idx],
                   make_ushort4(f2bf(w * s.x), f2bf(w * s.y), f2bf(w * s.z), f2bf(w * s.w)));
    if (!NORM) {
        nt_store4(&out_lo4[idx], s);
        return;
    }
    float sq = s.x * s.x + s.y * s.y + s.z * s.z + s.w * s.w;
    #pragma unroll
    for (int off = 8; off > 0; off >>= 1) sq += __shfl_xor(sq, off);
    float inv = 1.0f / fmaxf(sqrtf(sq), 1e-12f);
    float4 basev;
    if (VIRT_BASE)
        basev = (r < split) ? nt_load4(&fa4[idx])
                            : nt_load4(&fb4[((long long)(r - split) << 4) + l]);
    else
        basev = nt_load4(&accbuf4[idx]);
    float4 res;
    res.x = basev.x + s.x * inv;
    res.y = basev.y + s.y * inv;
    res.z = basev.z + s.z * inv;
    res.w = basev.w + s.w * inv;
    if (WRITE_ACC) nt_store4(&accbuf4[idx], res);
    if (out_lo4 && r < out_split) nt_store4(&out_lo4[idx], res);
    if (out_hi4 && r >= out_split) nt_store4(&out_hi4[((long long)(r - out_split) << 4) + l], res);
}

extern "C" void kernel_launch(void* const* d_in, const int* in_sizes, int n_in,
                              void* d_out, int out_size, void* d_ws, size_t ws_size,
                              hipStream_t stream) {
    const float* users   = (const float*)d_in[0];
    const float* items   = (const float*)d_in[1];
    const float* bundles = (const float*)d_in[2];
    const int*   aff_rows = (const int*)d_in[3];
    const int*   aff_cols = (const int*)d_in[4];
    const int*   hist_rows = (const int*)d_in[6];
    const int*   hist_cols = (const int*)d_in[7];
    const int*   agg_rows = (const int*)d_in[9];
    const int*   agg_cols = (const int*)d_in[10];

    const int U = in_sizes[0] / FD;
    const int I = in_sizes[1] / FD;
    const int B = in_sizes[2] / FD;
    const int nnz0 = in_sizes[3];   // aff
    const int nnz1 = in_sizes[9];   // agg
    const int nnz2 = in_sizes[6];   // hist
    const int n1 = U + I;
    const int n2 = U + B;

    const int nb0 = (n1 + BRS - 1) / BRS;
    const int nb1 = (B + BRS - 1) / BRS;
    const int nb2 = (n2 + BRS - 1) / BRS;
    const int nbtot = nb0 + nb1 + nb2;
    const int nch0 = (int)gridFor(nnz0, CH);
    const int nch1 = (int)gridFor(nnz1, CH);
    const int nch2 = (int)gridFor(nnz2, CH);
    const int nchtot = nch0 + nch1 + nch2;
    const long long nnztot = (long long)nnz0 + nnz1 + nnz2;
    const int hoff1 = nch0 * nb0;
    const int hoff2 = hoff1 + nch1 * nb1;
    const int roff1 = n1 + 1;
    const int roff2 = roff1 + B + 1;

    float* out = (float*)d_out;
    const long long n1e = (long long)n1 * FD;
    const long long Ue  = (long long)U * FD;
    const long long Be  = (long long)B * FD;

    // ---- workspace layout ----
    int*     etmp   = (int*)d_ws;                        // nnztot ints (26 MB)
    int*     epack  = etmp + nnztot;                     // nnztot ints
    ushort4* cat16  = (ushort4*)(epack + nnztot);        // n1*16 ushort4
    ushort4* nxt16  = cat16 + (long long)n1 * 16;        // n1*16 ushort4
    float*   acc    = (float*)(nxt16 + (long long)n1 * 16); // n1e f32
    int*     bptr   = (int*)(acc + n1e);                 // nbtot+3
    int*     gcount = bptr + (nbtot + 3);                // nbtot
    int*     row_ptr = gcount + nbtot;                   // (n1+1)+(B+1)+(n2+1)
    int*     h_blk  = row_ptr + roff2 + (n2 + 1);        // ~345K ints
    // overlays:
    unsigned short* rank = (unsigned short*)epack;       // nnztot ushorts (dead before epack written)
    ushort4* aggtab16 = (ushort4*)etmp;                  // I*16 ushort4 (etmp dead after sort)

    const int BLK = 256;
    const float4* users4   = (const float4*)users;
    const float4* items4   = (const float4*)items;
    const float4* bundles4 = (const float4*)bundles;
    float4* acc4 = (float4*)acc;
    float4* out4 = (float4*)out;

    const long long qU = (long long)U * 16;
    const long long qI = (long long)I * 16;
    const long long qB = (long long)B * 16;
    const long long tA = (long long)n1 * 16;
    const long long tH = (long long)n2 * 16;
    const long long tG = (long long)B * 16;

    // ---- batched CSR build (all 3 graphs) ----
    zero_int_kernel<<<gridFor(nbtot, BLK), BLK, 0, stream>>>(gcount, nbtot);
    bcount_rank_kernel<<<nchtot, 512, 0, stream>>>(
        aff_rows, agg_rows, hist_rows, nnz0, nnz1, nnz2,
        nb0, nb1, nb2, nch0, nch1, hoff1, hoff2, gcount, rank, h_blk);
    bscan_kernel<<<3, 1024, 0, stream>>>(gcount, nb0, nb1, nb2, nnz0, nnz1, nnz2, bptr);
    bchunk_base_kernel<<<nbtot, 64, 0, stream>>>(bptr, nb0, nb1, nb2,
                                                 nch0, nch1, nch2, hoff1, hoff2, h_blk);
    bscatter_kernel<<<gridFor(nnztot, BLK), BLK, 0, stream>>>(
        aff_rows, aff_cols, agg_rows, agg_cols, hist_rows, hist_cols,
        nnz0, nnz1, nnz2, nb0, nb1, nb2, hoff1, hoff2, rank, h_blk, etmp);
    blocal_sort_kernel<<<nbtot, 512, 0, stream>>>(bptr, etmp, epack, row_ptr,
                                                  nb0, nb1, nb2, n1, B, n2, roff1, roff2);

    // ---- aff propagate over (U+I) nodes ----
    pack2w_bf16_kernel<<<gridFor(qU + qI, BLK), BLK, 0, stream>>>(
        users4, qU, items4, qI, row_ptr, cat16);
    spmm_gather_bf16_kernel<0, true, true, true, true><<<gridFor(tA, BLK), BLK, 0, stream>>>(
        row_ptr, epack, cat16, users4, items4, U,
        nxt16, acc4, nullptr, nullptr, 0, n1, 0.5f);
    spmm_gather_bf16_kernel<0, false, false, true, true><<<gridFor(tA, BLK), BLK, 0, stream>>>(
        row_ptr, epack, nxt16, nullptr, nullptr, 0,
        nullptr, acc4, out4, nullptr, U, n1, 1.0f / 3.0f);

    // ---- aff_bundles = agg_spmm(bf16(aff items acc)) -> out[2U : 2U+B] ----
    pack1_bf16_kernel<<<gridFor(qI, BLK), BLK, 0, stream>>>(acc4 + qU, qI, aggtab16);
    spmm_gather_bf16_kernel<1, false, false, false, false><<<gridFor(tG, BLK), BLK, 0, stream>>>(
        row_ptr + roff1, epack, aggtab16, nullptr, nullptr, 0,
        nullptr, nullptr, (float4*)(out + 2 * Ue), nullptr, 0, B, 1.0f);

    // ---- hist propagate over (U+B) nodes ----
    pack2w_bf16_kernel<<<gridFor(qU + qB, BLK), BLK, 0, stream>>>(
        users4, qU, bundles4, qB, row_ptr + roff2, cat16);
    spmm_gather_bf16_kernel<0, true, true, true, true><<<gridFor(tH, BLK), BLK, 0, stream>>>(
        row_ptr + roff2, epack, cat16, users4, bundles4, U,
        nxt16, acc4, nullptr, nullptr, 0, n2, 0.5f);
    spmm_gather_bf16_kernel<0, false, false, true, false><<<gridFor(tH, BLK), BLK, 0, stream>>>(
        row_ptr + roff2, epack, nxt16, nullptr, nullptr, 0,
        nullptr, acc4, (float4*)(out + Ue), (float4*)(out + 2 * Ue + Be), U, n2, 1.0f / 3.0f);
}

// Round 16
// 362.763 us; speedup vs baseline: 1.1387x; 1.1387x over previous
//
#include <hip/hip_runtime.h>

#define FD 64          // feature dim
#define BRS 256        // rows per bucket
#define BR_SHIFT 8
#define COL_BITS 18
#define COL_MASK 0x3FFFF
#define NBMAX 640      // max bucket count per graph (aff: ceil(150016/256)=587)
#define CH 8192        // edges per chunk
#define CH_SHIFT 13

// ---------------- utility ----------------

static __global__ void zero_int_kernel(int* __restrict__ p, int n) {
    int i = blockIdx.x * blockDim.x + threadIdx.x;
    if (i < n) p[i] = 0;
}

static inline unsigned gridFor(long long n, int block) {
    return (unsigned)((n + block - 1) / block);
}

static __device__ inline unsigned short f2bf(float x) {
    unsigned u = __float_as_uint(x);
    unsigned r = ((u >> 16) & 1u) + 0x7FFFu;
    return (unsigned short)((u + r) >> 16);
}
static __device__ inline float bf2f(unsigned short h) {
    return __uint_as_float((unsigned)h << 16);
}

// pack concat(a,b) f32 quads -> bf16 quads, folding column weight f(deg)=1/(sqrt(deg)+eps)
static __global__ void pack2w_bf16_kernel(const float4* __restrict__ a, long long aq,
                                          const float4* __restrict__ b, long long bq,
                                          const int* __restrict__ rp,
                                          ushort4* __restrict__ dst) {
    long long i = (long long)blockIdx.x * blockDim.x + threadIdx.x;
    if (i >= aq + bq) return;
    int node = (int)(i >> 4);
    float w = 1.0f / (sqrtf((float)(rp[node + 1] - rp[node])) + 1e-8f);
    float4 f = (i < aq) ? a[i] : b[i - aq];
    dst[i] = make_ushort4(f2bf(w * f.x), f2bf(w * f.y), f2bf(w * f.z), f2bf(w * f.w));
}

// ---------------- batched CSR build over 3 graphs ----------------
// g0=aff, g1=agg, g2=hist. Edge positions are GLOBAL (offset by graph edge base).

// per-chunk LDS histogram -> per-edge rank (ushort), per-chunk hist h_blk, global gcount
static __global__ void bcount_rank_kernel(const int* __restrict__ r0, const int* __restrict__ r1,
                                          const int* __restrict__ r2,
                                          int nnz0, int nnz1, int nnz2,
                                          int nb0, int nb1, int nb2,
                                          int nch0, int nch1,
                                          int hoff1, int hoff2,
                                          int* __restrict__ gcount,
                                          unsigned short* __restrict__ rank,
                                          int* __restrict__ h_blk) {
    int blk = blockIdx.x;
    const int* rows; int nnz, nb, chl, hbase, gbase; long long ebase;
    if (blk < nch0)              { rows = r0; nnz = nnz0; nb = nb0; chl = blk;               hbase = 0;     gbase = 0;         ebase = 0; }
    else if (blk < nch0 + nch1)  { rows = r1; nnz = nnz1; nb = nb1; chl = blk - nch0;        hbase = hoff1; gbase = nb0;       ebase = nnz0; }
    else                         { rows = r2; nnz = nnz2; nb = nb2; chl = blk - nch0 - nch1; hbase = hoff2; gbase = nb0 + nb1; ebase = (long long)nnz0 + nnz1; }
    __shared__ int h[NBMAX];
    long long c0 = (long long)chl << CH_SHIFT;
    int cnt = (int)(((long long)nnz - c0) < CH ? ((long long)nnz - c0) : CH);
    for (int i = threadIdx.x; i < nb; i += blockDim.x) h[i] = 0;
    __syncthreads();
    for (int i = threadIdx.x; i < cnt; i += blockDim.x)
        rank[ebase + c0 + i] = (unsigned short)atomicAdd(&h[rows[c0 + i] >> BR_SHIFT], 1);
    __syncthreads();
    int* hb = h_blk + hbase + (long long)chl * nb;
    for (int i = threadIdx.x; i < nb; i += blockDim.x) {
        int c = h[i];
        hb[i] = c;
        if (c) atomicAdd(&gcount[gbase + i], c);
    }
}

// one block per graph: exclusive scan of nb_g counts -> bptr (GLOBAL edge positions)
static __global__ void bscan_kernel(const int* __restrict__ gcount,
                                    int nb0, int nb1, int nb2,
                                    int nnz0, int nnz1, int nnz2,
                                    int* __restrict__ bptr) {
    __shared__ int tsum[1024];
    int g = blockIdx.x;
    int nb, gbase, pbase, nnz; long long ebase;
    if (g == 0)      { nb = nb0; gbase = 0;         pbase = 0;             ebase = 0;                       nnz = nnz0; }
    else if (g == 1) { nb = nb1; gbase = nb0;       pbase = nb0 + 1;       ebase = nnz0;                    nnz = nnz1; }
    else             { nb = nb2; gbase = nb0 + nb1; pbase = nb0 + nb1 + 2; ebase = (long long)nnz0 + nnz1;  nnz = nnz2; }
    int k = (nb + 1023) / 1024;
    int start = threadIdx.x * k;
    int s = 0;
    for (int i = 0; i < k; ++i) {
        int idx = start + i;
        if (idx < nb) s += gcount[gbase + idx];
    }
    tsum[threadIdx.x] = s;
    __syncthreads();
    for (int off = 1; off < 1024; off <<= 1) {
        int t = (threadIdx.x >= (unsigned)off) ? tsum[threadIdx.x - off] : 0;
        __syncthreads();
        tsum[threadIdx.x] += t;
        __syncthreads();
    }
    int run = (int)ebase + tsum[threadIdx.x] - s;
    for (int i = 0; i < k; ++i) {
        int idx = start + i;
        if (idx < nb) {
            bptr[pbase + idx] = run;
            run += gcount[gbase + idx];
        }
    }
    if (threadIdx.x == 0) bptr[pbase + nb] = (int)(ebase + nnz);
}

// one wave per bucket: scan per-(chunk,bucket) counts into base offsets (in place)
static __global__ void bchunk_base_kernel(const int* __restrict__ bptr,
                                          int nb0, int nb1, int nb2,
                                          int nch0, int nch1, int nch2,
                                          int hoff1, int hoff2,
                                          int* __restrict__ h_blk) {
    int b = blockIdx.x;
    int bl, nb, nch, hbase, pbase;
    if (b < nb0)            { bl = b;             nb = nb0; nch = nch0; hbase = 0;     pbase = 0; }
    else if (b < nb0 + nb1) { bl = b - nb0;       nb = nb1; nch = nch1; hbase = hoff1; pbase = nb0 + 1; }
    else                    { bl = b - nb0 - nb1; nb = nb2; nch = nch2; hbase = hoff2; pbase = nb0 + nb1 + 2; }
    int lane = threadIdx.x;
    int k = (nch + 63) / 64;
    int i0 = lane * k;
    int s = 0;
    for (int i = 0; i < k; ++i) {
        int blk = i0 + i;
        if (blk < nch) s += h_blk[hbase + (long long)blk * nb + bl];
    }
    int sc = s;
    #pragma unroll
    for (int off = 1; off < 64; off <<= 1) {
        int t = __shfl_up(sc, off);
        if (lane >= off) sc += t;
    }
    int run = bptr[pbase + bl] + sc - s;
    for (int i = 0; i < k; ++i) {
        int blk = i0 + i;
        if (blk < nch) {
            long long o = hbase + (long long)blk * nb + bl;
            int c = h_blk[o];
            h_blk[o] = run;
            run += c;
        }
    }
}

// pure scatter over all graphs: 1 edge/thread; 4B payload
// etmp[pos] = (row % BRS) << COL_BITS | col
static __global__ void bscatter_kernel(const int* __restrict__ r0, const int* __restrict__ c0p,
                                       const int* __restrict__ r1, const int* __restrict__ c1p,
                                       const int* __restrict__ r2, const int* __restrict__ c2p,
                                       int nnz0, int nnz1, int nnz2,
                                       int nb0, int nb1, int nb2,
                                       int hoff1, int hoff2,
                                       const unsigned short* __restrict__ rank,
                                       const int* __restrict__ base_blk,
                                       int* __restrict__ etmp) {
    long long t = (long long)blockIdx.x * blockDim.x + threadIdx.x;
    long long e1 = nnz0, e2 = (long long)nnz0 + nnz1, e3 = e2 + nnz2;
    if (t >= e3) return;
    const int* rows; const int* cols; long long i; int nb, hbase;
    if (t < e1)      { rows = r0; cols = c0p; i = t;      nb = nb0; hbase = 0; }
    else if (t < e2) { rows = r1; cols = c1p; i = t - e1; nb = nb1; hbase = hoff1; }
    else             { rows = r2; cols = c2p; i = t - e2; nb = nb2; hbase = hoff2; }
    int r = rows[i];
    int b = r >> BR_SHIFT;
    int pos = base_blk[hbase + (i >> CH_SHIFT) * (long long)nb + b] + rank[t];
    etmp[pos] = ((r & (BRS - 1)) << COL_BITS) | cols[i];
}

// per-bucket counting sort (256 rows/bucket, 512 threads) -> row-sorted epack + row_ptr
static __global__ void blocal_sort_kernel(const int* __restrict__ bptr,
                                          const int* __restrict__ etmp,
                                          int* __restrict__ epack,
                                          int* __restrict__ row_ptr,
                                          int nb0, int nb1, int nb2,
                                          int n0, int n1g, int n2g,
                                          int roff1, int roff2) {
    __shared__ int cnt[BRS];
    __shared__ int startS[BRS];
    __shared__ int wsum[8];
    int b = blockIdx.x;
    int bl, pbase, rbase, ng, nbg;
    if (b < nb0)            { bl = b;             pbase = 0;             rbase = 0;     ng = n0;  nbg = nb0; }
    else if (b < nb0 + nb1) { bl = b - nb0;       pbase = nb0 + 1;       rbase = roff1; ng = n1g; nbg = nb1; }
    else                    { bl = b - nb0 - nb1; pbase = nb0 + nb1 + 2; rbase = roff2; ng = n2g; nbg = nb2; }
    int beg = bptr[pbase + bl], end = bptr[pbase + bl + 1];
    int tid = threadIdx.x;                 // blockDim = 512
    if (tid < BRS) cnt[tid] = 0;
    __syncthreads();
    for (int e = beg + tid; e < end; e += blockDim.x)
        atomicAdd(&cnt[((unsigned)etmp[e]) >> COL_BITS], 1);
    __syncthreads();
    int v = (tid < BRS) ? cnt[tid] : 0;
    int s = v;
    int lane = tid & 63, wv = tid >> 6;    // waves 0..3 hold the 256 counters
    #pragma unroll
    for (int off = 1; off < 64; off <<= 1) {
        int t = __shfl_up(s, off);
        if (lane >= off) s += t;
    }
    if (tid < BRS && lane == 63) wsum[wv] = s;
    __syncthreads();
    if (tid == 0) {
        int run = 0;
        #pragma unroll
        for (int w = 0; w < BRS / 64; ++w) { int t = wsum[w]; wsum[w] = run; run += t; }
    }
    __syncthreads();
    if (tid < BRS) {
        int ex = s - v + wsum[wv];         // exclusive prefix
        startS[tid] = ex;
        int r = bl * BRS + tid;
        if (r < ng) row_ptr[rbase + r] = beg + ex;
        cnt[tid] = 0;
    }
    __syncthreads();
    for (int e = beg + tid; e < end; e += blockDim.x) {
        int p = etmp[e];
        int rl = ((unsigned)p) >> COL_BITS;
        int rk = atomicAdd(&cnt[rl], 1);
        epack[beg + startS[rl] + rk] = p & COL_MASK;
    }
    if (bl == 0 && tid == 0) row_ptr[rbase + ng] = bptr[pbase + nbg];
}

// ---------------- fused gather SpMM over bf16 table, 16 lanes/row x 4 dims ----------------
// WMODE 0: row weight w = 1/(sqrt(deg)+1e-8)  (sym-normalized graphs)
// WMODE 1: row weight w = 1/(deg+1e-8)        (agg graph)
// s = scale * w_r * sum_e tab16[col_e]   (column weight pre-folded into table)
// HI_BF16: rows >= out_split write bf16(res) to out_hi16 instead of f32 out_hi4
template <int WMODE, bool VIRT_BASE, bool WRITE_NXT16, bool NORM, bool WRITE_ACC, bool HI_BF16>
static __global__ void spmm_gather_bf16_kernel(const int* __restrict__ row_ptr,
                                               const int* __restrict__ epack,
                                               const ushort4* __restrict__ tab16,
                                               const float4* __restrict__ fa4,
                                               const float4* __restrict__ fb4, int split,
                                               ushort4* __restrict__ nxt16,
                                               float4* __restrict__ accbuf4,
                                               float4* __restrict__ out_lo4,
                                               float4* __restrict__ out_hi4,
                                               ushort4* __restrict__ out_hi16,
                                               int out_split, int n, float scale) {
    long long t = (long long)blockIdx.x * blockDim.x + threadIdx.x;
    int r = (int)(t >> 4);
    if (r >= n) return;
    int l = (int)(t & 15);
    int beg = row_ptr[r];
    int end = row_ptr[r + 1];
    float ax = 0.f, ay = 0.f, az = 0.f, aw = 0.f;
    int e = beg;
    for (; e + 7 < end; e += 8) {
        int c0 = epack[e];
        int c1 = epack[e + 1];
        int c2 = epack[e + 2];
        int c3 = epack[e + 3];
        int c4 = epack[e + 4];
        int c5 = epack[e + 5];
        int c6 = epack[e + 6];
        int c7 = epack[e + 7];
        ushort4 h0 = tab16[((long long)c0 << 4) + l];
        ushort4 h1 = tab16[((long long)c1 << 4) + l];
        ushort4 h2 = tab16[((long long)c2 << 4) + l];
        ushort4 h3 = tab16[((long long)c3 << 4) + l];
        ushort4 h4 = tab16[((long long)c4 << 4) + l];
        ushort4 h5 = tab16[((long long)c5 << 4) + l];
        ushort4 h6 = tab16[((long long)c6 << 4) + l];
        ushort4 h7 = tab16[((long long)c7 << 4) + l];
        ax += bf2f(h0.x); ay += bf2f(h0.y); az += bf2f(h0.z); aw += bf2f(h0.w);
        ax += bf2f(h1.x); ay += bf2f(h1.y); az += bf2f(h1.z); aw += bf2f(h1.w);
        ax += bf2f(h2.x); ay += bf2f(h2.y); az += bf2f(h2.z); aw += bf2f(h2.w);
        ax += bf2f(h3.x); ay += bf2f(h3.y); az += bf2f(h3.z); aw += bf2f(h3.w);
        ax += bf2f(h4.x); ay += bf2f(h4.y); az += bf2f(h4.z); aw += bf2f(h4.w);
        ax += bf2f(h5.x); ay += bf2f(h5.y); az += bf2f(h5.z); aw += bf2f(h5.w);
        ax += bf2f(h6.x); ay += bf2f(h6.y); az += bf2f(h6.z); aw += bf2f(h6.w);
        ax += bf2f(h7.x); ay += bf2f(h7.y); az += bf2f(h7.z); aw += bf2f(h7.w);
    }
    for (; e + 3 < end; e += 4) {
        int c0 = epack[e];
        int c1 = epack[e + 1];
        int c2 = epack[e + 2];
        int c3 = epack[e + 3];
        ushort4 h0 = tab16[((long long)c0 << 4) + l];
        ushort4 h1 = tab16[((long long)c1 << 4) + l];
        ushort4 h2 = tab16[((long long)c2 << 4) + l];
        ushort4 h3 = tab16[((long long)c3 << 4) + l];
        ax += bf2f(h0.x); ay += bf2f(h0.y); az += bf2f(h0.z); aw += bf2f(h0.w);
        ax += bf2f(h1.x); ay += bf2f(h1.y); az += bf2f(h1.z); aw += bf2f(h1.w);
        ax += bf2f(h2.x); ay += bf2f(h2.y); az += bf2f(h2.z); aw += bf2f(h2.w);
        ax += bf2f(h3.x); ay += bf2f(h3.y); az += bf2f(h3.z); aw += bf2f(h3.w);
    }
    for (; e < end; ++e) {
        int c = epack[e];
        ushort4 h = tab16[((long long)c << 4) + l];
        ax += bf2f(h.x); ay += bf2f(h.y); az += bf2f(h.z); aw += bf2f(h.w);
    }
    float deg = (float)(end - beg);
    float w = (WMODE == 0) ? (1.0f / (sqrtf(deg) + 1e-8f)) : (1.0f / (deg + 1e-8f));
    float m = scale * w;
    float4 s;
    s.x = ax * m; s.y = ay * m; s.z = az * m; s.w = aw * m;
    long long idx = ((long long)r << 4) + l;
    if (WRITE_NXT16)  // layer-2 table entry: f_r * s_r
        nxt16[idx] = make_ushort4(f2bf(w * s.x), f2bf(w * s.y), f2bf(w * s.z), f2bf(w * s.w));
    if (!NORM) {
        out_lo4[idx] = s;
        return;
    }
    float sq = s.x * s.x + s.y * s.y + s.z * s.z + s.w * s.w;
    #pragma unroll
    for (int off = 8; off > 0; off >>= 1) sq += __shfl_xor(sq, off);
    float inv = 1.0f / fmaxf(sqrtf(sq), 1e-12f);
    float4 basev;
    if (VIRT_BASE)
        basev = (r < split) ? fa4[idx] : fb4[((long long)(r - split) << 4) + l];
    else
        basev = accbuf4[idx];
    float4 res;
    res.x = basev.x + s.x * inv;
    res.y = basev.y + s.y * inv;
    res.z = basev.z + s.z * inv;
    res.w = basev.w + s.w * inv;
    if (WRITE_ACC) accbuf4[idx] = res;
    if (out_lo4 && r < out_split) out_lo4[idx] = res;
    if (r >= out_split) {
        long long hidx = ((long long)(r - out_split) << 4) + l;
        if (HI_BF16)
            out_hi16[hidx] = make_ushort4(f2bf(res.x), f2bf(res.y), f2bf(res.z), f2bf(res.w));
        else if (out_hi4)
            out_hi4[hidx] = res;
    }
}

extern "C" void kernel_launch(void* const* d_in, const int* in_sizes, int n_in,
                              void* d_out, int out_size, void* d_ws, size_t ws_size,
                              hipStream_t stream) {
    const float* users   = (const float*)d_in[0];
    const float* items   = (const float*)d_in[1];
    const float* bundles = (const float*)d_in[2];
    const int*   aff_rows = (const int*)d_in[3];
    const int*   aff_cols = (const int*)d_in[4];
    const int*   hist_rows = (const int*)d_in[6];
    const int*   hist_cols = (const int*)d_in[7];
    const int*   agg_rows = (const int*)d_in[9];
    const int*   agg_cols = (const int*)d_in[10];

    const int U = in_sizes[0] / FD;
    const int I = in_sizes[1] / FD;
    const int B = in_sizes[2] / FD;
    const int nnz0 = in_sizes[3];   // aff
    const int nnz1 = in_sizes[9];   // agg
    const int nnz2 = in_sizes[6];   // hist
    const int n1 = U + I;
    const int n2 = U + B;

    const int nb0 = (n1 + BRS - 1) / BRS;
    const int nb1 = (B + BRS - 1) / BRS;
    const int nb2 = (n2 + BRS - 1) / BRS;
    const int nbtot = nb0 + nb1 + nb2;
    const int nch0 = (int)gridFor(nnz0, CH);
    const int nch1 = (int)gridFor(nnz1, CH);
    const int nch2 = (int)gridFor(nnz2, CH);
    const int nchtot = nch0 + nch1 + nch2;
    const long long nnztot = (long long)nnz0 + nnz1 + nnz2;
    const int hoff1 = nch0 * nb0;
    const int hoff2 = hoff1 + nch1 * nb1;
    const int roff1 = n1 + 1;
    const int roff2 = roff1 + B + 1;

    float* out = (float*)d_out;
    const long long n1e = (long long)n1 * FD;
    const long long Ue  = (long long)U * FD;
    const long long Be  = (long long)B * FD;

    // ---- workspace layout ----
    int*     etmp   = (int*)d_ws;                        // nnztot ints (26 MB)
    int*     epack  = etmp + nnztot;                     // nnztot ints
    ushort4* cat16  = (ushort4*)(epack + nnztot);        // n1*16 ushort4
    ushort4* nxt16  = cat16 + (long long)n1 * 16;        // n1*16 ushort4
    float*   acc    = (float*)(nxt16 + (long long)n1 * 16); // n1e f32
    int*     bptr   = (int*)(acc + n1e);                 // nbtot+3
    int*     gcount = bptr + (nbtot + 3);                // nbtot
    int*     row_ptr = gcount + nbtot;                   // (n1+1)+(B+1)+(n2+1)
    int*     h_blk  = row_ptr + roff2 + (n2 + 1);        // ~345K ints
    // overlays:
    unsigned short* rank = (unsigned short*)epack;       // nnztot ushorts (dead before epack written)
    ushort4* aggtab16 = (ushort4*)etmp;                  // I*16 ushort4 (etmp dead after sort)

    const int BLK = 256;
    const float4* users4   = (const float4*)users;
    const float4* items4   = (const float4*)items;
    const float4* bundles4 = (const float4*)bundles;
    float4* acc4 = (float4*)acc;
    float4* out4 = (float4*)out;

    const long long qU = (long long)U * 16;
    const long long qI = (long long)I * 16;
    const long long qB = (long long)B * 16;
    const long long tA = (long long)n1 * 16;
    const long long tH = (long long)n2 * 16;
    const long long tG = (long long)B * 16;

    // ---- batched CSR build (all 3 graphs) ----
    zero_int_kernel<<<gridFor(nbtot, BLK), BLK, 0, stream>>>(gcount, nbtot);
    bcount_rank_kernel<<<nchtot, 512, 0, stream>>>(
        aff_rows, agg_rows, hist_rows, nnz0, nnz1, nnz2,
        nb0, nb1, nb2, nch0, nch1, hoff1, hoff2, gcount, rank, h_blk);
    bscan_kernel<<<3, 1024, 0, stream>>>(gcount, nb0, nb1, nb2, nnz0, nnz1, nnz2, bptr);
    bchunk_base_kernel<<<nbtot, 64, 0, stream>>>(bptr, nb0, nb1, nb2,
                                                 nch0, nch1, nch2, hoff1, hoff2, h_blk);
    bscatter_kernel<<<gridFor(nnztot, BLK), BLK, 0, stream>>>(
        aff_rows, aff_cols, agg_rows, agg_cols, hist_rows, hist_cols,
        nnz0, nnz1, nnz2, nb0, nb1, nb2, hoff1, hoff2, rank, h_blk, etmp);
    blocal_sort_kernel<<<nbtot, 512, 0, stream>>>(bptr, etmp, epack, row_ptr,
                                                  nb0, nb1, nb2, n1, B, n2, roff1, roff2);

    // ---- aff propagate over (U+I) nodes ----
    pack2w_bf16_kernel<<<gridFor(qU + qI, BLK), BLK, 0, stream>>>(
        users4, qU, items4, qI, row_ptr, cat16);
    // L1: nxt16 = bf16(w*s); acc = concat + l2norm(s)
    spmm_gather_bf16_kernel<0, true, true, true, true, false><<<gridFor(tA, BLK), BLK, 0, stream>>>(
        row_ptr, epack, cat16, users4, items4, U,
        nxt16, acc4, nullptr, nullptr, nullptr, 0, n1, 0.5f);
    // L2: res = acc + l2norm(s/3); r<U -> out (aff_users, f32); r>=U -> aggtab16 (bf16)
    spmm_gather_bf16_kernel<0, false, false, true, false, true><<<gridFor(tA, BLK), BLK, 0, stream>>>(
        row_ptr, epack, nxt16, nullptr, nullptr, 0,
        nullptr, acc4, out4, nullptr, aggtab16, U, n1, 1.0f / 3.0f);

    // ---- aff_bundles = agg_spmm(aggtab16) -> out[2U : 2U+B] ----
    spmm_gather_bf16_kernel<1, false, false, false, false, false><<<gridFor(tG, BLK), BLK, 0, stream>>>(
        row_ptr + roff1, epack, aggtab16, nullptr, nullptr, 0,
        nullptr, nullptr, (float4*)(out + 2 * Ue), nullptr, nullptr, 0, B, 1.0f);

    // ---- hist propagate over (U+B) nodes ----
    pack2w_bf16_kernel<<<gridFor(qU + qB, BLK), BLK, 0, stream>>>(
        users4, qU, bundles4, qB, row_ptr + roff2, cat16);
    spmm_gather_bf16_kernel<0, true, true, true, true, false><<<gridFor(tH, BLK), BLK, 0, stream>>>(
        row_ptr + roff2, epack, cat16, users4, bundles4, U,
        nxt16, acc4, nullptr, nullptr, nullptr, 0, n2, 0.5f);
    // L2: res = acc + l2norm(s/3); r<U -> hist_users, r>=U -> hist_bundles (both f32)
    spmm_gather_bf16_kernel<0, false, false, true, false, false><<<gridFor(tH, BLK), BLK, 0, stream>>>(
        row_ptr + roff2, epack, nxt16, nullptr, nullptr, 0,
        nullptr, acc4, (float4*)(out + Ue), (float4*)(out + 2 * Ue + Be), nullptr, U, n2, 1.0f / 3.0f);
}

// Round 17
// 351.544 us; speedup vs baseline: 1.1750x; 1.0319x over previous
//
#include <hip/hip_runtime.h>

#define FD 64          // feature dim
#define BRS 256        // rows per bucket
#define BR_SHIFT 8
#define COL_BITS 18
#define COL_MASK 0x3FFFF
#define NBMAX 640      // max bucket count per graph (aff: ceil(150016/256)=587)
#define CH 8192        // edges per chunk
#define CH_SHIFT 13
#define NXCD 8

// ---------------- utility ----------------

static __global__ void zero_int_kernel(int* __restrict__ p, int n) {
    int i = blockIdx.x * blockDim.x + threadIdx.x;
    if (i < n) p[i] = 0;
}

static inline unsigned gridFor(long long n, int block) {
    return (unsigned)((n + block - 1) / block);
}

static __device__ inline unsigned short f2bf(float x) {
    unsigned u = __float_as_uint(x);
    unsigned r = ((u >> 16) & 1u) + 0x7FFFu;
    return (unsigned short)((u + r) >> 16);
}
static __device__ inline float bf2f(unsigned short h) {
    return __uint_as_float((unsigned)h << 16);
}

// bijective XCD swizzle (m204): consecutive swizzled ids map to one XCD's
// contiguous range, assuming round-robin workgroup->XCD dispatch.
static __device__ inline int xcd_swizzle(int bid, int nblk) {
    int q = nblk >> 3, r = nblk & 7;
    int x = bid & 7, i = bid >> 3;
    return (x < r ? x * (q + 1) : r * (q + 1) + (x - r) * q) + i;
}

// pack concat(a,b) f32 quads -> bf16 quads, folding column weight f(deg)=1/(sqrt(deg)+eps)
static __global__ void pack2w_bf16_kernel(const float4* __restrict__ a, long long aq,
                                          const float4* __restrict__ b, long long bq,
                                          const int* __restrict__ rp,
                                          ushort4* __restrict__ dst) {
    long long i = (long long)blockIdx.x * blockDim.x + threadIdx.x;
    if (i >= aq + bq) return;
    int node = (int)(i >> 4);
    float w = 1.0f / (sqrtf((float)(rp[node + 1] - rp[node])) + 1e-8f);
    float4 f = (i < aq) ? a[i] : b[i - aq];
    dst[i] = make_ushort4(f2bf(w * f.x), f2bf(w * f.y), f2bf(w * f.z), f2bf(w * f.w));
}

// ---------------- batched CSR build over 3 graphs ----------------
// g0=aff, g1=agg, g2=hist. Edge positions are GLOBAL (offset by graph edge base).

// per-chunk LDS histogram -> per-edge rank (ushort), per-chunk hist h_blk, global gcount
static __global__ void bcount_rank_kernel(const int* __restrict__ r0, const int* __restrict__ r1,
                                          const int* __restrict__ r2,
                                          int nnz0, int nnz1, int nnz2,
                                          int nb0, int nb1, int nb2,
                                          int nch0, int nch1,
                                          int hoff1, int hoff2,
                                          int* __restrict__ gcount,
                                          unsigned short* __restrict__ rank,
                                          int* __restrict__ h_blk) {
    int blk = blockIdx.x;
    const int* rows; int nnz, nb, chl, hbase, gbase; long long ebase;
    if (blk < nch0)              { rows = r0; nnz = nnz0; nb = nb0; chl = blk;               hbase = 0;     gbase = 0;         ebase = 0; }
    else if (blk < nch0 + nch1)  { rows = r1; nnz = nnz1; nb = nb1; chl = blk - nch0;        hbase = hoff1; gbase = nb0;       ebase = nnz0; }
    else                         { rows = r2; nnz = nnz2; nb = nb2; chl = blk - nch0 - nch1; hbase = hoff2; gbase = nb0 + nb1; ebase = (long long)nnz0 + nnz1; }
    __shared__ int h[NBMAX];
    long long c0 = (long long)chl << CH_SHIFT;
    int cnt = (int)(((long long)nnz - c0) < CH ? ((long long)nnz - c0) : CH);
    for (int i = threadIdx.x; i < nb; i += blockDim.x) h[i] = 0;
    __syncthreads();
    for (int i = threadIdx.x; i < cnt; i += blockDim.x)
        rank[ebase + c0 + i] = (unsigned short)atomicAdd(&h[rows[c0 + i] >> BR_SHIFT], 1);
    __syncthreads();
    int* hb = h_blk + hbase + (long long)chl * nb;
    for (int i = threadIdx.x; i < nb; i += blockDim.x) {
        int c = h[i];
        hb[i] = c;
        if (c) atomicAdd(&gcount[gbase + i], c);
    }
}

// one block per graph: exclusive scan of nb_g counts -> bptr (GLOBAL edge positions)
static __global__ void bscan_kernel(const int* __restrict__ gcount,
                                    int nb0, int nb1, int nb2,
                                    int nnz0, int nnz1, int nnz2,
                                    int* __restrict__ bptr) {
    __shared__ int tsum[1024];
    int g = blockIdx.x;
    int nb, gbase, pbase, nnz; long long ebase;
    if (g == 0)      { nb = nb0; gbase = 0;         pbase = 0;             ebase = 0;                       nnz = nnz0; }
    else if (g == 1) { nb = nb1; gbase = nb0;       pbase = nb0 + 1;       ebase = nnz0;                    nnz = nnz1; }
    else             { nb = nb2; gbase = nb0 + nb1; pbase = nb0 + nb1 + 2; ebase = (long long)nnz0 + nnz1;  nnz = nnz2; }
    int k = (nb + 1023) / 1024;
    int start = threadIdx.x * k;
    int s = 0;
    for (int i = 0; i < k; ++i) {
        int idx = start + i;
        if (idx < nb) s += gcount[gbase + idx];
    }
    tsum[threadIdx.x] = s;
    __syncthreads();
    for (int off = 1; off < 1024; off <<= 1) {
        int t = (threadIdx.x >= (unsigned)off) ? tsum[threadIdx.x - off] : 0;
        __syncthreads();
        tsum[threadIdx.x] += t;
        __syncthreads();
    }
    int run = (int)ebase + tsum[threadIdx.x] - s;
    for (int i = 0; i < k; ++i) {
        int idx = start + i;
        if (idx < nb) {
            bptr[pbase + idx] = run;
            run += gcount[gbase + idx];
        }
    }
    if (threadIdx.x == 0) bptr[pbase + nb] = (int)(ebase + nnz);
}

// one wave per bucket: scan per-(chunk,bucket) counts into base offsets (in place)
static __global__ void bchunk_base_kernel(const int* __restrict__ bptr,
                                          int nb0, int nb1, int nb2,
                                          int nch0, int nch1, int nch2,
                                          int hoff1, int hoff2,
                                          int* __restrict__ h_blk) {
    int b = blockIdx.x;
    int bl, nb, nch, hbase, pbase;
    if (b < nb0)            { bl = b;             nb = nb0; nch = nch0; hbase = 0;     pbase = 0; }
    else if (b < nb0 + nb1) { bl = b - nb0;       nb = nb1; nch = nch1; hbase = hoff1; pbase = nb0 + 1; }
    else                    { bl = b - nb0 - nb1; nb = nb2; nch = nch2; hbase = hoff2; pbase = nb0 + nb1 + 2; }
    int lane = threadIdx.x;
    int k = (nch + 63) / 64;
    int i0 = lane * k;
    int s = 0;
    for (int i = 0; i < k; ++i) {
        int blk = i0 + i;
        if (blk < nch) s += h_blk[hbase + (long long)blk * nb + bl];
    }
    int sc = s;
    #pragma unroll
    for (int off = 1; off < 64; off <<= 1) {
        int t = __shfl_up(sc, off);
        if (lane >= off) sc += t;
    }
    int run = bptr[pbase + bl] + sc - s;
    for (int i = 0; i < k; ++i) {
        int blk = i0 + i;
        if (blk < nch) {
            long long o = hbase + (long long)blk * nb + bl;
            int c = h_blk[o];
            h_blk[o] = run;
            run += c;
        }
    }
}

// pure scatter over all graphs: 1 edge/thread; 4B payload
// etmp[pos] = (row % BRS) << COL_BITS | col
// XCD-swizzled block index: each XCD owns a contiguous edge slice so partial
// etmp lines merge in that XCD's L2 before writeback.
static __global__ void bscatter_kernel(const int* __restrict__ r0, const int* __restrict__ c0p,
                                       const int* __restrict__ r1, const int* __restrict__ c1p,
                                       const int* __restrict__ r2, const int* __restrict__ c2p,
                                       int nnz0, int nnz1, int nnz2,
                                       int nb0, int nb1, int nb2,
                                       int hoff1, int hoff2,
                                       const unsigned short* __restrict__ rank,
                                       const int* __restrict__ base_blk,
                                       int* __restrict__ etmp) {
    int swz = xcd_swizzle(blockIdx.x, gridDim.x);
    long long t = (long long)swz * blockDim.x + threadIdx.x;
    long long e1 = nnz0, e2 = (long long)nnz0 + nnz1, e3 = e2 + nnz2;
    if (t >= e3) return;
    const int* rows; const int* cols; long long i; int nb, hbase;
    if (t < e1)      { rows = r0; cols = c0p; i = t;      nb = nb0; hbase = 0; }
    else if (t < e2) { rows = r1; cols = c1p; i = t - e1; nb = nb1; hbase = hoff1; }
    else             { rows = r2; cols = c2p; i = t - e2; nb = nb2; hbase = hoff2; }
    int r = rows[i];
    int b = r >> BR_SHIFT;
    int pos = base_blk[hbase + (i >> CH_SHIFT) * (long long)nb + b] + rank[t];
    etmp[pos] = ((r & (BRS - 1)) << COL_BITS) | cols[i];
}

// per-bucket counting sort (256 rows/bucket, 512 threads) -> row-sorted epack + row_ptr
static __global__ void blocal_sort_kernel(const int* __restrict__ bptr,
                                          const int* __restrict__ etmp,
                                          int* __restrict__ epack,
                                          int* __restrict__ row_ptr,
                                          int nb0, int nb1, int nb2,
                                          int n0, int n1g, int n2g,
                                          int roff1, int roff2) {
    __shared__ int cnt[BRS];
    __shared__ int startS[BRS];
    __shared__ int wsum[8];
    int b = blockIdx.x;
    int bl, pbase, rbase, ng, nbg;
    if (b < nb0)            { bl = b;             pbase = 0;             rbase = 0;     ng = n0;  nbg = nb0; }
    else if (b < nb0 + nb1) { bl = b - nb0;       pbase = nb0 + 1;       rbase = roff1; ng = n1g; nbg = nb1; }
    else                    { bl = b - nb0 - nb1; pbase = nb0 + nb1 + 2; rbase = roff2; ng = n2g; nbg = nb2; }
    int beg = bptr[pbase + bl], end = bptr[pbase + bl + 1];
    int tid = threadIdx.x;                 // blockDim = 512
    if (tid < BRS) cnt[tid] = 0;
    __syncthreads();
    for (int e = beg + tid; e < end; e += blockDim.x)
        atomicAdd(&cnt[((unsigned)etmp[e]) >> COL_BITS], 1);
    __syncthreads();
    int v = (tid < BRS) ? cnt[tid] : 0;
    int s = v;
    int lane = tid & 63, wv = tid >> 6;    // waves 0..3 hold the 256 counters
    #pragma unroll
    for (int off = 1; off < 64; off <<= 1) {
        int t = __shfl_up(s, off);
        if (lane >= off) s += t;
    }
    if (tid < BRS && lane == 63) wsum[wv] = s;
    __syncthreads();
    if (tid == 0) {
        int run = 0;
        #pragma unroll
        for (int w = 0; w < BRS / 64; ++w) { int t = wsum[w]; wsum[w] = run; run += t; }
    }
    __syncthreads();
    if (tid < BRS) {
        int ex = s - v + wsum[wv];         // exclusive prefix
        startS[tid] = ex;
        int r = bl * BRS + tid;
        if (r < ng) row_ptr[rbase + r] = beg + ex;
        cnt[tid] = 0;
    }
    __syncthreads();
    for (int e = beg + tid; e < end; e += blockDim.x) {
        int p = etmp[e];
        int rl = ((unsigned)p) >> COL_BITS;
        int rk = atomicAdd(&cnt[rl], 1);
        epack[beg + startS[rl] + rk] = p & COL_MASK;
    }
    if (bl == 0 && tid == 0) row_ptr[rbase + ng] = bptr[pbase + nbg];
}

// ---------------- fused gather SpMM over bf16 table, 16 lanes/row x 4 dims ----------------
// WMODE 0: row weight w = 1/(sqrt(deg)+1e-8)  (sym-normalized graphs)
// WMODE 1: row weight w = 1/(deg+1e-8)        (agg graph)
// s = scale * w_r * sum_e tab16[col_e]   (column weight pre-folded into table)
// HI_BF16: rows >= out_split write bf16(res) to out_hi16 instead of f32 out_hi4
template <int WMODE, bool VIRT_BASE, bool WRITE_NXT16, bool NORM, bool WRITE_ACC, bool HI_BF16>
static __global__ void spmm_gather_bf16_kernel(const int* __restrict__ row_ptr,
                                               const int* __restrict__ epack,
                                               const ushort4* __restrict__ tab16,
                                               const float4* __restrict__ fa4,
                                               const float4* __restrict__ fb4, int split,
                                               ushort4* __restrict__ nxt16,
                                               float4* __restrict__ accbuf4,
                                               float4* __restrict__ out_lo4,
                                               float4* __restrict__ out_hi4,
                                               ushort4* __restrict__ out_hi16,
                                               int out_split, int n, float scale) {
    long long t = (long long)blockIdx.x * blockDim.x + threadIdx.x;
    int r = (int)(t >> 4);
    if (r >= n) return;
    int l = (int)(t & 15);
    int beg = row_ptr[r];
    int end = row_ptr[r + 1];
    float ax = 0.f, ay = 0.f, az = 0.f, aw = 0.f;
    int e = beg;
    for (; e + 7 < end; e += 8) {
        int c0 = epack[e];
        int c1 = epack[e + 1];
        int c2 = epack[e + 2];
        int c3 = epack[e + 3];
        int c4 = epack[e + 4];
        int c5 = epack[e + 5];
        int c6 = epack[e + 6];
        int c7 = epack[e + 7];
        ushort4 h0 = tab16[((long long)c0 << 4) + l];
        ushort4 h1 = tab16[((long long)c1 << 4) + l];
        ushort4 h2 = tab16[((long long)c2 << 4) + l];
        ushort4 h3 = tab16[((long long)c3 << 4) + l];
        ushort4 h4 = tab16[((long long)c4 << 4) + l];
        ushort4 h5 = tab16[((long long)c5 << 4) + l];
        ushort4 h6 = tab16[((long long)c6 << 4) + l];
        ushort4 h7 = tab16[((long long)c7 << 4) + l];
        ax += bf2f(h0.x); ay += bf2f(h0.y); az += bf2f(h0.z); aw += bf2f(h0.w);
        ax += bf2f(h1.x); ay += bf2f(h1.y); az += bf2f(h1.z); aw += bf2f(h1.w);
        ax += bf2f(h2.x); ay += bf2f(h2.y); az += bf2f(h2.z); aw += bf2f(h2.w);
        ax += bf2f(h3.x); ay += bf2f(h3.y); az += bf2f(h3.z); aw += bf2f(h3.w);
        ax += bf2f(h4.x); ay += bf2f(h4.y); az += bf2f(h4.z); aw += bf2f(h4.w);
        ax += bf2f(h5.x); ay += bf2f(h5.y); az += bf2f(h5.z); aw += bf2f(h5.w);
        ax += bf2f(h6.x); ay += bf2f(h6.y); az += bf2f(h6.z); aw += bf2f(h6.w);
        ax += bf2f(h7.x); ay += bf2f(h7.y); az += bf2f(h7.z); aw += bf2f(h7.w);
    }
    for (; e + 3 < end; e += 4) {
        int c0 = epack[e];
        int c1 = epack[e + 1];
        int c2 = epack[e + 2];
        int c3 = epack[e + 3];
        ushort4 h0 = tab16[((long long)c0 << 4) + l];
        ushort4 h1 = tab16[((long long)c1 << 4) + l];
        ushort4 h2 = tab16[((long long)c2 << 4) + l];
        ushort4 h3 = tab16[((long long)c3 << 4) + l];
        ax += bf2f(h0.x); ay += bf2f(h0.y); az += bf2f(h0.z); aw += bf2f(h0.w);
        ax += bf2f(h1.x); ay += bf2f(h1.y); az += bf2f(h1.z); aw += bf2f(h1.w);
        ax += bf2f(h2.x); ay += bf2f(h2.y); az += bf2f(h2.z); aw += bf2f(h2.w);
        ax += bf2f(h3.x); ay += bf2f(h3.y); az += bf2f(h3.z); aw += bf2f(h3.w);
    }
    for (; e < end; ++e) {
        int c = epack[e];
        ushort4 h = tab16[((long long)c << 4) + l];
        ax += bf2f(h.x); ay += bf2f(h.y); az += bf2f(h.z); aw += bf2f(h.w);
    }
    float deg = (float)(end - beg);
    float w = (WMODE == 0) ? (1.0f / (sqrtf(deg) + 1e-8f)) : (1.0f / (deg + 1e-8f));
    float m = scale * w;
    float4 s;
    s.x = ax * m; s.y = ay * m; s.z = az * m; s.w = aw * m;
    long long idx = ((long long)r << 4) + l;
    if (WRITE_NXT16)  // layer-2 table entry: f_r * s_r
        nxt16[idx] = make_ushort4(f2bf(w * s.x), f2bf(w * s.y), f2bf(w * s.z), f2bf(w * s.w));
    if (!NORM) {
        out_lo4[idx] = s;
        return;
    }
    float sq = s.x * s.x + s.y * s.y + s.z * s.z + s.w * s.w;
    #pragma unroll
    for (int off = 8; off > 0; off >>= 1) sq += __shfl_xor(sq, off);
    float inv = 1.0f / fmaxf(sqrtf(sq), 1e-12f);
    float4 basev;
    if (VIRT_BASE)
        basev = (r < split) ? fa4[idx] : fb4[((long long)(r - split) << 4) + l];
    else
        basev = accbuf4[idx];
    float4 res;
    res.x = basev.x + s.x * inv;
    res.y = basev.y + s.y * inv;
    res.z = basev.z + s.z * inv;
    res.w = basev.w + s.w * inv;
    if (WRITE_ACC) accbuf4[idx] = res;
    if (out_lo4 && r < out_split) out_lo4[idx] = res;
    if (r >= out_split) {
        long long hidx = ((long long)(r - out_split) << 4) + l;
        if (HI_BF16)
            out_hi16[hidx] = make_ushort4(f2bf(res.x), f2bf(res.y), f2bf(res.z), f2bf(res.w));
        else if (out_hi4)
            out_hi4[hidx] = res;
    }
}

extern "C" void kernel_launch(void* const* d_in, const int* in_sizes, int n_in,
                              void* d_out, int out_size, void* d_ws, size_t ws_size,
                              hipStream_t stream) {
    const float* users   = (const float*)d_in[0];
    const float* items   = (const float*)d_in[1];
    const float* bundles = (const float*)d_in[2];
    const int*   aff_rows = (const int*)d_in[3];
    const int*   aff_cols = (const int*)d_in[4];
    const int*   hist_rows = (const int*)d_in[6];
    const int*   hist_cols = (const int*)d_in[7];
    const int*   agg_rows = (const int*)d_in[9];
    const int*   agg_cols = (const int*)d_in[10];

    const int U = in_sizes[0] / FD;
    const int I = in_sizes[1] / FD;
    const int B = in_sizes[2] / FD;
    const int nnz0 = in_sizes[3];   // aff
    const int nnz1 = in_sizes[9];   // agg
    const int nnz2 = in_sizes[6];   // hist
    const int n1 = U + I;
    const int n2 = U + B;

    const int nb0 = (n1 + BRS - 1) / BRS;
    const int nb1 = (B + BRS - 1) / BRS;
    const int nb2 = (n2 + BRS - 1) / BRS;
    const int nbtot = nb0 + nb1 + nb2;
    const int nch0 = (int)gridFor(nnz0, CH);
    const int nch1 = (int)gridFor(nnz1, CH);
    const int nch2 = (int)gridFor(nnz2, CH);
    const int nchtot = nch0 + nch1 + nch2;
    const long long nnztot = (long long)nnz0 + nnz1 + nnz2;
    const int hoff1 = nch0 * nb0;
    const int hoff2 = hoff1 + nch1 * nb1;
    const int roff1 = n1 + 1;
    const int roff2 = roff1 + B + 1;

    float* out = (float*)d_out;
    const long long n1e = (long long)n1 * FD;
    const long long Ue  = (long long)U * FD;
    const long long Be  = (long long)B * FD;

    // ---- workspace layout ----
    int*     etmp   = (int*)d_ws;                        // nnztot ints (26 MB)
    int*     epack  = etmp + nnztot;                     // nnztot ints
    ushort4* cat16  = (ushort4*)(epack + nnztot);        // n1*16 ushort4
    ushort4* nxt16  = cat16 + (long long)n1 * 16;        // n1*16 ushort4
    float*   acc    = (float*)(nxt16 + (long long)n1 * 16); // n1e f32
    int*     bptr   = (int*)(acc + n1e);                 // nbtot+3
    int*     gcount = bptr + (nbtot + 3);                // nbtot
    int*     row_ptr = gcount + nbtot;                   // (n1+1)+(B+1)+(n2+1)
    int*     h_blk  = row_ptr + roff2 + (n2 + 1);        // ~345K ints
    // overlays:
    unsigned short* rank = (unsigned short*)epack;       // nnztot ushorts (dead before epack written)
    ushort4* aggtab16 = (ushort4*)etmp;                  // I*16 ushort4 (etmp dead after sort)

    const int BLK = 256;
    const float4* users4   = (const float4*)users;
    const float4* items4   = (const float4*)items;
    const float4* bundles4 = (const float4*)bundles;
    float4* acc4 = (float4*)acc;
    float4* out4 = (float4*)out;

    const long long qU = (long long)U * 16;
    const long long qI = (long long)I * 16;
    const long long qB = (long long)B * 16;
    const long long tA = (long long)n1 * 16;
    const long long tH = (long long)n2 * 16;
    const long long tG = (long long)B * 16;

    // ---- batched CSR build (all 3 graphs) ----
    zero_int_kernel<<<gridFor(nbtot, BLK), BLK, 0, stream>>>(gcount, nbtot);
    bcount_rank_kernel<<<nchtot, 512, 0, stream>>>(
        aff_rows, agg_rows, hist_rows, nnz0, nnz1, nnz2,
        nb0, nb1, nb2, nch0, nch1, hoff1, hoff2, gcount, rank, h_blk);
    bscan_kernel<<<3, 1024, 0, stream>>>(gcount, nb0, nb1, nb2, nnz0, nnz1, nnz2, bptr);
    bchunk_base_kernel<<<nbtot, 64, 0, stream>>>(bptr, nb0, nb1, nb2,
                                                 nch0, nch1, nch2, hoff1, hoff2, h_blk);
    bscatter_kernel<<<gridFor(nnztot, BLK), BLK, 0, stream>>>(
        aff_rows, aff_cols, agg_rows, agg_cols, hist_rows, hist_cols,
        nnz0, nnz1, nnz2, nb0, nb1, nb2, hoff1, hoff2, rank, h_blk, etmp);
    blocal_sort_kernel<<<nbtot, 512, 0, stream>>>(bptr, etmp, epack, row_ptr,
                                                  nb0, nb1, nb2, n1, B, n2, roff1, roff2);

    // ---- aff propagate over (U+I) nodes ----
    pack2w_bf16_kernel<<<gridFor(qU + qI, BLK), BLK, 0, stream>>>(
        users4, qU, items4, qI, row_ptr, cat16);
    // L1: nxt16 = bf16(w*s); acc = concat + l2norm(s)
    spmm_gather_bf16_kernel<0, true, true, true, true, false><<<gridFor(tA, BLK), BLK, 0, stream>>>(
        row_ptr, epack, cat16, users4, items4, U,
        nxt16, acc4, nullptr, nullptr, nullptr, 0, n1, 0.5f);
    // L2: res = acc + l2norm(s/3); r<U -> out (aff_users, f32); r>=U -> aggtab16 (bf16)
    spmm_gather_bf16_kernel<0, false, false, true, false, true><<<gridFor(tA, BLK), BLK, 0, stream>>>(
        row_ptr, epack, nxt16, nullptr, nullptr, 0,
        nullptr, acc4, out4, nullptr, aggtab16, U, n1, 1.0f / 3.0f);

    // ---- aff_bundles = agg_spmm(aggtab16) -> out[2U : 2U+B] ----
    spmm_gather_bf16_kernel<1, false, false, false, false, false><<<gridFor(tG, BLK), BLK, 0, stream>>>(
        row_ptr + roff1, epack, aggtab16, nullptr, nullptr, 0,
        nullptr, nullptr, (float4*)(out + 2 * Ue), nullptr, nullptr, 0, B, 1.0f);

    // ---- hist propagate over (U+B) nodes ----
    pack2w_bf16_kernel<<<gridFor(qU + qB, BLK), BLK, 0, stream>>>(
        users4, qU, bundles4, qB, row_ptr + roff2, cat16);
    spmm_gather_bf16_kernel<0, true, true, true, true, false><<<gridFor(tH, BLK), BLK, 0, stream>>>(
        row_ptr + roff2, epack, cat16, users4, bundles4, U,
        nxt16, acc4, nullptr, nullptr, nullptr, 0, n2, 0.5f);
    // L2: res = acc + l2norm(s/3); r<U -> hist_users, r>=U -> hist_bundles (both f32)
    spmm_gather_bf16_kernel<0, false, false, true, false, false><<<gridFor(tH, BLK), BLK, 0, stream>>>(
        row_ptr + roff2, epack, nxt16, nullptr, nullptr, 0,
        nullptr, acc4, (float4*)(out + Ue), (float4*)(out + 2 * Ue + Be), nullptr, U, n2, 1.0f / 3.0f);
}